// Round 22
// baseline (42.644 us; speedup 1.0000x reference)
//
#include <hip/hip_runtime.h>

#define ROWS 256
#define COLS 512
#define BATCH 512
#define NC 5
#define DEG 16
#define EPG (ROWS * DEG)       /* 4096 edges per graph */
#define NPG (ROWS + COLS)      /* 768 nodes per graph  */
#define NT 512
#define EPT (EPG / NT)         /* 8 edges per thread per graph */
#define GPB 2                  /* graphs per block */
#define EPSF 1e-7f
#define MV_W (EPG + 3 * COLS)  /* 5632 words: dst bins, 4-aligned starts */
#define MC_W (EPG + 3 * ROWS)  /* 4864 words: src bins, 4-aligned starts */

typedef unsigned short u16;
typedef unsigned int   u32;
typedef float v2f __attribute__((ext_vector_type(2)));

__device__ __forceinline__ float sigmoid_f(float a) {
    return 1.0f / (1.0f + __expf(-a));
}
__device__ __forceinline__ float tanh_f(float a) {
    return fmaf(2.0f, 1.0f / (1.0f + __expf(-2.0f * a)), -1.0f);
}

__global__ __launch_bounds__(NT, 2) void gnni_kernel(
    const float* __restrict__ x,
    const int*   __restrict__ eidx,
    const float* __restrict__ w1_1, const float* __restrict__ b1_1,
    const float* __restrict__ w2_1, const float* __restrict__ b2_1,
    const float* __restrict__ wih_1, const float* __restrict__ whh_1,
    const float* __restrict__ bih_1, const float* __restrict__ bhh_1,
    const float* __restrict__ w1_2, const float* __restrict__ b1_2,
    const float* __restrict__ w2_2, const float* __restrict__ b2_2,
    const float* __restrict__ wih_2, const float* __restrict__ whh_2,
    const float* __restrict__ bih_2, const float* __restrict__ bhh_2,
    float* __restrict__ out)
{
    __shared__ float msgV[GPB][MV_W];
    __shared__ float msgC[GPB][MC_W];
    __shared__ u32  cntd[GPB][COLS];
    __shared__ u32  cnts[GPB][ROWS];
    __shared__ u16  beg_v[GPB][COLS];
    __shared__ u16  deg_v[GPB][COLS];
    __shared__ u16  beg_c[GPB][ROWS];
    __shared__ u16  deg_c[GPB][ROWS];
    __shared__ float hc[GPB][ROWS];
    __shared__ float hv[GPB][COLS];
    __shared__ u32  wsum[GPB][8];
    __shared__ u32  wsum2[GPB][4];

    const int tid  = threadIdx.x;
    const int lane = tid & 63;
    const int wid  = tid >> 6;
    const int b    = blockIdx.x;             // 0..255
    int  baseg[GPB];
    long ebaseg[GPB];
    #pragma unroll
    for (int g = 0; g < GPB; ++g) {
        baseg[g]  = (GPB * b + g) * NPG;
        ebaseg[g] = (long)(GPB * b + g) * EPG;
    }

    // ---- vectorized edge loads for both graphs ----
    u32 aS[GPB][EPT], aD[GPB][EPT];
    #pragma unroll
    for (int g = 0; g < GPB; ++g) {
        const int4 sa = *(const int4*)(eidx + ebaseg[g] + tid * 8);
        const int4 sb = *(const int4*)(eidx + ebaseg[g] + tid * 8 + 4);
        const int4 da = *(const int4*)(eidx + (long)BATCH * EPG + ebaseg[g] + tid * 8);
        const int4 db = *(const int4*)(eidx + (long)BATCH * EPG + ebaseg[g] + tid * 8 + 4);
        const int sarr[EPT] = {sa.x, sa.y, sa.z, sa.w, sb.x, sb.y, sb.z, sb.w};
        const int darr[EPT] = {da.x, da.y, da.z, da.w, db.x, db.y, db.z, db.w};
        #pragma unroll
        for (int i = 0; i < EPT; ++i) {
            aS[g][i] = (u32)(sarr[i] - baseg[g]) << 2;   // byte offset, src in [0,256)
            aD[g][i] = (u32)(darr[i] - baseg[g]) << 2;   // byte offset, dst raw in [0,512)
        }
    }

    // ---- zero msg buffers ONCE (pads stay 0) + counters ----
    for (int i = tid; i < MV_W; i += NT) { msgV[0][i] = 0.0f; msgV[1][i] = 0.0f; }
    for (int i = tid; i < MC_W; i += NT) { msgC[0][i] = 0.0f; msgC[1][i] = 0.0f; }
    cntd[0][tid] = 0; cntd[1][tid] = 0;
    if (tid < ROWS) { cnts[0][tid] = 0; cnts[1][tid] = 0; }
    __syncthreads();

    // ---- count both keys, both graphs ----
    #pragma unroll
    for (int g = 0; g < GPB; ++g)
        #pragma unroll
        for (int i = 0; i < EPT; ++i) {
            atomicAdd(&cntd[g][aD[g][i] >> 2], 1u);
            atomicAdd(&cnts[g][aS[g][i] >> 2], 1u);
        }
    __syncthreads();

    // ---- dual wave-shuffle scans (ILP-2 over graphs) ----
    u32 myd[GPB], acd[GPB], scv[GPB];
    #pragma unroll
    for (int g = 0; g < GPB; ++g) {
        myd[g] = cntd[g][tid];
        acd[g] = (myd[g] + 3u) & ~3u;
        scv[g] = acd[g];
    }
    #pragma unroll
    for (int st = 1; st < 64; st <<= 1) {
        u32 t0 = __shfl_up(scv[0], st);
        u32 t1 = __shfl_up(scv[1], st);
        if (lane >= st) { scv[0] += t0; scv[1] += t1; }
    }
    if (lane == 63) { wsum[0][wid] = scv[0]; wsum[1][wid] = scv[1]; }
    u32 mys[GPB] = {0, 0}, acs[GPB] = {0, 0}, scc[GPB] = {0, 0};
    if (tid < ROWS) {
        #pragma unroll
        for (int g = 0; g < GPB; ++g) {
            mys[g] = cnts[g][tid];
            acs[g] = (mys[g] + 3u) & ~3u;
            scc[g] = acs[g];
        }
        #pragma unroll
        for (int st = 1; st < 64; st <<= 1) {
            u32 t0 = __shfl_up(scc[0], st);
            u32 t1 = __shfl_up(scc[1], st);
            if (lane >= st) { scc[0] += t0; scc[1] += t1; }
        }
        if (lane == 63) { wsum2[0][wid] = scc[0]; wsum2[1][wid] = scc[1]; }
    }
    __syncthreads();
    if (tid < 8) {
        u32 v0 = wsum[0][tid], v1 = wsum[1][tid];
        #pragma unroll
        for (int st = 1; st < 8; st <<= 1) {
            u32 t0 = __shfl_up(v0, st);
            u32 t1 = __shfl_up(v1, st);
            if (tid >= st) { v0 += t0; v1 += t1; }
        }
        wsum[0][tid] = v0; wsum[1][tid] = v1;
    } else if (tid < 12) {
        u32 v0 = wsum2[0][tid - 8], v1 = wsum2[1][tid - 8];
        #pragma unroll
        for (int st = 1; st < 4; st <<= 1) {
            u32 t0 = __shfl_up(v0, st);
            u32 t1 = __shfl_up(v1, st);
            if (tid - 8 >= st) { v0 += t0; v1 += t1; }
        }
        wsum2[0][tid - 8] = v0; wsum2[1][tid - 8] = v1;
    }
    __syncthreads();
    #pragma unroll
    for (int g = 0; g < GPB; ++g) {
        u32 inc  = scv[g] + (wid ? wsum[g][wid - 1] : 0u);
        u32 begv = inc - acd[g];
        beg_v[g][tid] = (u16)begv;
        deg_v[g][tid] = (u16)myd[g];
        cntd[g][tid]  = begv;
    }
    if (tid < ROWS) {
        #pragma unroll
        for (int g = 0; g < GPB; ++g) {
            u32 inc  = scc[g] + (wid ? wsum2[g][wid - 1] : 0u);
            u32 begc = inc - acs[g];
            beg_c[g][tid] = (u16)begc;
            deg_c[g][tid] = (u16)mys[g];
            cnts[g][tid]  = begc;
            hc[g][tid] = x[baseg[g] + tid];
        }
    }
    float hvreg[GPB];
    #pragma unroll
    for (int g = 0; g < GPB; ++g) {
        hvreg[g] = x[baseg[g] + ROWS + tid];
        hv[g][tid] = hvreg[g];
    }
    __syncthreads();

    // ---- placement cursors -> byte offsets ----
    u32 p1B[GPB][EPT], p2B[GPB][EPT];
    #pragma unroll
    for (int g = 0; g < GPB; ++g)
        #pragma unroll
        for (int i = 0; i < EPT; ++i) {
            p1B[g][i] = atomicAdd(&cntd[g][aD[g][i] >> 2], 1u) << 2;
            p2B[g][i] = atomicAdd(&cnts[g][aS[g][i] >> 2], 1u) << 2;
        }

    // ---- weights as float2 pairs (wave-uniform) ----
    v2f A1[5], C1[5], B1[5], W1[5], A2[5], C2[5], B2[5], W2[5];
    #pragma unroll
    for (int j = 0; j < 5; ++j) {
        A1[j] = (v2f){w1_1[4*j],     w1_1[4*j + 2]};
        C1[j] = (v2f){w1_1[4*j + 1], w1_1[4*j + 3]};
        B1[j] = (v2f){b1_1[2*j],     b1_1[2*j + 1]};
        W1[j] = (v2f){w2_1[2*j],     w2_1[2*j + 1]};
        A2[j] = (v2f){w1_2[4*j],     w1_2[4*j + 2]};
        C2[j] = (v2f){w1_2[4*j + 1], w1_2[4*j + 3]};
        B2[j] = (v2f){b1_2[2*j],     b1_2[2*j + 1]};
        W2[j] = (v2f){w2_2[2*j],     w2_2[2*j + 1]};
    }
    const float b2_1s = b2_1[0], b2_2s = b2_2[0];
    const v2f zero2 = (v2f){0.0f, 0.0f};

    // ---- initial hv caches ----
    float hvs[GPB][EPT];
    #pragma unroll
    for (int g = 0; g < GPB; ++g)
        #pragma unroll
        for (int i = 0; i < EPT; ++i)
            hvs[g][i] = *(const float*)((const char*)&hv[g][0] + aD[g][i]);

    for (int it = 0; it < NC; ++it) {
        // hc frozen this iteration -> cache gathers (16 independent reads)
        float hcs[GPB][EPT];
        #pragma unroll
        for (int g = 0; g < GPB; ++g)
            #pragma unroll
            for (int i = 0; i < EPT; ++i)
                hcs[g][i] = *(const float*)((const char*)&hc[g][0] + aS[g][i]);

        // ===== phase 1 pass A: 16 gather-free MLPs -> scatter msgV =====
        #pragma unroll
        for (int g = 0; g < GPB; ++g)
            #pragma unroll
            for (int i = 0; i < EPT; ++i) {
                const float xj = hcs[g][i];
                const float xi = hvs[g][i];
                const v2f xj2 = (v2f){xj, xj}, xi2 = (v2f){xi, xi};
                v2f acc = (v2f){b2_1s, 0.0f};
                #pragma unroll
                for (int j = 0; j < 5; ++j) {
                    v2f t = __builtin_elementwise_fma(C1[j], xi2, B1[j]);
                    t = __builtin_elementwise_fma(A1[j], xj2, t);
                    t = __builtin_elementwise_max(t, zero2);
                    acc = __builtin_elementwise_fma(W1[j], t, acc);
                }
                *(float*)((char*)&msgV[g][0] + p1B[g][i]) = acc.x + acc.y;
            }
        __syncthreads();

        // ===== phase 1 pass B: var owner x2 — float4 gathers + GRUs =====
        #pragma unroll
        for (int g = 0; g < GPB; ++g) {
            const int beg = beg_v[g][tid];
            const int deg = deg_v[g][tid];
            const float4* mp = (const float4*)&msgV[g][beg];
            float4 a4 = {0.0f, 0.0f, 0.0f, 0.0f};
            #pragma unroll
            for (int k = 0; k < 5; ++k) {
                if (4 * k < deg) {
                    const float4 q = mp[k];
                    a4.x += q.x; a4.y += q.y; a4.z += q.z; a4.w += q.w;
                }
            }
            float hx = (a4.x + a4.y) + (a4.z + a4.w);
            for (int e = beg + 20; e < beg + deg; ++e) hx += msgV[g][e];
            const float xg = hvreg[g];
            float gi0 = fmaf(wih_1[0], xg, bih_1[0]);
            float gi1 = fmaf(wih_1[1], xg, bih_1[1]);
            float gi2 = fmaf(wih_1[2], xg, bih_1[2]);
            float gh0 = fmaf(whh_1[0], hx, bhh_1[0]);
            float gh1 = fmaf(whh_1[1], hx, bhh_1[1]);
            float gh2 = fmaf(whh_1[2], hx, bhh_1[2]);
            float r = sigmoid_f(gi0 + gh0);
            float z = sigmoid_f(gi1 + gh1);
            float n = tanh_f(fmaf(r, gh2, gi2));
            hvreg[g] = fmaf(1.0f - z, n, z * hx);
            hv[g][tid] = hvreg[g];
        }
        __syncthreads();

        // ===== phase 2 pass A: refresh hv caches, 16 MLPs -> scatter msgC =====
        #pragma unroll
        for (int g = 0; g < GPB; ++g)
            #pragma unroll
            for (int i = 0; i < EPT; ++i)
                hvs[g][i] = *(const float*)((const char*)&hv[g][0] + aD[g][i]);
        #pragma unroll
        for (int g = 0; g < GPB; ++g)
            #pragma unroll
            for (int i = 0; i < EPT; ++i) {
                const float xi = hcs[g][i];
                const float xj = hvs[g][i];
                const v2f xj2 = (v2f){xj, xj}, xi2 = (v2f){xi, xi};
                v2f acc = (v2f){b2_2s, 0.0f};
                #pragma unroll
                for (int j = 0; j < 5; ++j) {
                    v2f t = __builtin_elementwise_fma(C2[j], xi2, B2[j]);
                    t = __builtin_elementwise_fma(A2[j], xj2, t);
                    t = __builtin_elementwise_max(t, zero2);
                    acc = __builtin_elementwise_fma(W2[j], t, acc);
                }
                *(float*)((char*)&msgC[g][0] + p2B[g][i]) = acc.x + acc.y;
            }
        __syncthreads();

        // ===== phase 2 pass B: lane-pair per check x2 — float4 gathers + GRUs =====
        {
            const int c    = tid >> 1;
            const int half = tid & 1;
            #pragma unroll
            for (int g = 0; g < GPB; ++g) {
                const int beg = beg_c[g][c];
                const int deg = deg_c[g][c];
                const float4* mp = (const float4*)&msgC[g][beg];
                float4 a4 = {0.0f, 0.0f, 0.0f, 0.0f};
                #pragma unroll
                for (int k = 0; k < 4; ++k) {
                    const int ch = half + 2 * k;
                    if (4 * ch < deg) {
                        const float4 q = mp[ch];
                        a4.x += q.x; a4.y += q.y; a4.z += q.z; a4.w += q.w;
                    }
                }
                float part = (a4.x + a4.y) + (a4.z + a4.w);
                for (int e = beg + 32 + half; e < beg + deg; e += 2) part += msgC[g][e];
                part += __shfl_xor(part, 1);
                if (half == 0) {
                    const float hx = part;
                    const float xg = hc[g][c];
                    float gi0 = fmaf(wih_2[0], xg, bih_2[0]);
                    float gi1 = fmaf(wih_2[1], xg, bih_2[1]);
                    float gi2 = fmaf(wih_2[2], xg, bih_2[2]);
                    float gh0 = fmaf(whh_2[0], hx, bhh_2[0]);
                    float gh1 = fmaf(whh_2[1], hx, bhh_2[1]);
                    float gh2 = fmaf(whh_2[2], hx, bhh_2[2]);
                    float r = sigmoid_f(gi0 + gh0);
                    float z = sigmoid_f(gi1 + gh1);
                    float n = tanh_f(fmaf(r, gh2, gi2));
                    hc[g][c] = fmaf(1.0f - z, n, z * hx);
                }
            }
        }
        __syncthreads();
    }

    // ---- epilogue: out = clip(sigmoid(-h), eps, 1-eps), both graphs ----
    #pragma unroll
    for (int g = 0; g < GPB; ++g) {
        float sgm = 1.0f / (1.0f + __expf(hvreg[g]));
        out[baseg[g] + ROWS + tid] = fminf(fmaxf(sgm, EPSF), 1.0f - EPSF);
        if (tid < ROWS) {
            float s2 = 1.0f / (1.0f + __expf(hc[g][tid]));
            out[baseg[g] + tid] = fminf(fmaxf(s2, EPSF), 1.0f - EPSF);
        }
    }
}

extern "C" void kernel_launch(void* const* d_in, const int* in_sizes, int n_in,
                              void* d_out, int out_size, void* d_ws, size_t ws_size,
                              hipStream_t stream) {
    const float* x    = (const float*)d_in[0];
    const int*   eidx = (const int*)d_in[1];
    gnni_kernel<<<BATCH / GPB, NT, 0, stream>>>(
        x, eidx,
        (const float*)d_in[2],  (const float*)d_in[3],
        (const float*)d_in[4],  (const float*)d_in[5],
        (const float*)d_in[6],  (const float*)d_in[7],
        (const float*)d_in[8],  (const float*)d_in[9],
        (const float*)d_in[10], (const float*)d_in[11],
        (const float*)d_in[12], (const float*)d_in[13],
        (const float*)d_in[14], (const float*)d_in[15],
        (const float*)d_in[16], (const float*)d_in[17],
        (float*)d_out);
}

// Round 23
// 38.355 us; speedup vs baseline: 1.1118x; 1.1118x over previous
//
#include <hip/hip_runtime.h>

#define ROWS 256
#define COLS 512
#define BATCH 512
#define NC 5
#define DEG 16
#define EPG (ROWS * DEG)       /* 4096 edges per graph */
#define NPG (ROWS + COLS)      /* 768 nodes per graph  */
#define NT 512
#define EPT (EPG / NT)         /* 8 edges per thread   */
#define EPSF 1e-7f
#define MV_W (EPG + 3 * COLS)  /* 5632 words: dst bins, 4-aligned starts */
#define MC_W (EPG + 3 * ROWS)  /* 4864 words: src bins, 4-aligned starts */

typedef unsigned short u16;
typedef unsigned int   u32;
typedef float v2f __attribute__((ext_vector_type(2)));

__device__ __forceinline__ float sigmoid_f(float a) {
    return 1.0f / (1.0f + __expf(-a));
}
__device__ __forceinline__ float tanh_f(float a) {
    return fmaf(2.0f, 1.0f / (1.0f + __expf(-2.0f * a)), -1.0f);
}

__global__ __launch_bounds__(NT, 4) void gnni_kernel(
    const float* __restrict__ x,
    const int*   __restrict__ eidx,
    const float* __restrict__ w1_1, const float* __restrict__ b1_1,
    const float* __restrict__ w2_1, const float* __restrict__ b2_1,
    const float* __restrict__ wih_1, const float* __restrict__ whh_1,
    const float* __restrict__ bih_1, const float* __restrict__ bhh_1,
    const float* __restrict__ w1_2, const float* __restrict__ b1_2,
    const float* __restrict__ w2_2, const float* __restrict__ b2_2,
    const float* __restrict__ wih_2, const float* __restrict__ whh_2,
    const float* __restrict__ bih_2, const float* __restrict__ bhh_2,
    float* __restrict__ out)
{
    __shared__ float msgV[MV_W];      // phase-1 messages (dst bins, padded)
    __shared__ float msgC[MC_W];      // phase-2 messages (src bins, padded)
    __shared__ u32  cntd[COLS];       // dst counts -> placement cursor
    __shared__ u32  cnts[ROWS];       // src counts -> placement cursor
    __shared__ u16  beg_v[COLS];      // aligned bin start (var)
    __shared__ u16  deg_v[COLS];      // bin degree (var)
    __shared__ u16  beg_c[ROWS];      // aligned bin start (check)
    __shared__ u16  deg_c[ROWS];      // bin degree (check)
    __shared__ float hc[ROWS];
    __shared__ float hv[COLS];
    __shared__ u32  wsum[8];
    __shared__ u32  wsum2[4];

    const int tid  = threadIdx.x;
    const int lane = tid & 63;
    const int wid  = tid >> 6;
    const int b    = blockIdx.x;
    const int base = b * NPG;
    const long ebase = (long)b * EPG;

    // ---- vectorized edge load: thread tid owns edges [tid*8, tid*8+8) ----
    const int4 sa = *(const int4*)(eidx + ebase + tid * 8);
    const int4 sb = *(const int4*)(eidx + ebase + tid * 8 + 4);
    const int4 da = *(const int4*)(eidx + (long)BATCH * EPG + ebase + tid * 8);
    const int4 db = *(const int4*)(eidx + (long)BATCH * EPG + ebase + tid * 8 + 4);
    const int sarr[EPT] = {sa.x, sa.y, sa.z, sa.w, sb.x, sb.y, sb.z, sb.w};
    const int darr[EPT] = {da.x, da.y, da.z, da.w, db.x, db.y, db.z, db.w};
    u32 ep[EPT];
    #pragma unroll
    for (int i = 0; i < EPT; ++i)
        ep[i] = (u32)(sarr[i] - base) | ((u32)(darr[i] - base) << 16);

    // ---- zero msg buffers ONCE (pad words must stay 0 forever) ----
    for (int i = tid; i < MV_W; i += NT) msgV[i] = 0.0f;
    for (int i = tid; i < MC_W; i += NT) msgC[i] = 0.0f;
    cntd[tid] = 0;
    if (tid < ROWS) cnts[tid] = 0;
    __syncthreads();

    // ---- count both keys ----
    #pragma unroll
    for (int i = 0; i < EPT; ++i) {
        atomicAdd(&cntd[ep[i] >> 16], 1u);
        atomicAdd(&cnts[ep[i] & 0xffffu], 1u);
    }
    __syncthreads();

    // ---- wave-shuffle scans over ALIGNED counts -> aligned bin starts ----
    u32 myd = cntd[tid];
    u32 acd = (myd + 3u) & ~3u;
    u32 scv = acd;
    #pragma unroll
    for (int st = 1; st < 64; st <<= 1) {
        u32 t = __shfl_up(scv, st);
        if (lane >= st) scv += t;
    }
    if (lane == 63) wsum[wid] = scv;
    u32 mys = 0, acs = 0, scc = 0;
    if (tid < ROWS) {
        mys = cnts[tid];
        acs = (mys + 3u) & ~3u;
        scc = acs;
        #pragma unroll
        for (int st = 1; st < 64; st <<= 1) {
            u32 t = __shfl_up(scc, st);
            if (lane >= st) scc += t;
        }
        if (lane == 63) wsum2[wid] = scc;
    }
    __syncthreads();
    if (tid < 8) {
        u32 v = wsum[tid];
        #pragma unroll
        for (int st = 1; st < 8; st <<= 1) {
            u32 t = __shfl_up(v, st);
            if (tid >= st) v += t;
        }
        wsum[tid] = v;
    } else if (tid < 12) {
        u32 v = wsum2[tid - 8];
        #pragma unroll
        for (int st = 1; st < 4; st <<= 1) {
            u32 t = __shfl_up(v, st);
            if (tid - 8 >= st) v += t;
        }
        wsum2[tid - 8] = v;
    }
    __syncthreads();
    {
        u32 inc  = scv + (wid ? wsum[wid - 1] : 0u);
        u32 begv = inc - acd;                  // 4-aligned exclusive start
        beg_v[tid] = (u16)begv;
        deg_v[tid] = (u16)myd;
        cntd[tid]  = begv;                     // placement cursor
    }
    if (tid < ROWS) {
        u32 inc  = scc + (wid ? wsum2[wid - 1] : 0u);
        u32 begc = inc - acs;
        beg_c[tid] = (u16)begc;
        deg_c[tid] = (u16)mys;
        cnts[tid]  = begc;
        hc[tid] = x[base + tid];
    }
    float hvreg = x[base + ROWS + tid];
    hv[tid] = hvreg;
    __syncthreads();

    // ---- placement: loop-invariant byte offsets in VGPRs ----
    u32 aS[EPT], aD[EPT], p1B[EPT], p2B[EPT];
    #pragma unroll
    for (int i = 0; i < EPT; ++i) {
        const u32 p = ep[i];
        const u32 s = p & 0xffffu;
        const u32 d = p >> 16;
        aS[i]  = s << 2;
        aD[i]  = d << 2;
        p1B[i] = atomicAdd(&cntd[d], 1u) << 2;
        p2B[i] = atomicAdd(&cnts[s], 1u) << 2;
    }

    // ---- weights as float2 pairs (wave-uniform -> SGPRs) ----
    v2f A1[5], C1[5], B1[5], W1[5], A2[5], C2[5], B2[5], W2[5];
    #pragma unroll
    for (int j = 0; j < 5; ++j) {
        A1[j] = (v2f){w1_1[4*j],     w1_1[4*j + 2]};
        C1[j] = (v2f){w1_1[4*j + 1], w1_1[4*j + 3]};
        B1[j] = (v2f){b1_1[2*j],     b1_1[2*j + 1]};
        W1[j] = (v2f){w2_1[2*j],     w2_1[2*j + 1]};
        A2[j] = (v2f){w1_2[4*j],     w1_2[4*j + 2]};
        C2[j] = (v2f){w1_2[4*j + 1], w1_2[4*j + 3]};
        B2[j] = (v2f){b1_2[2*j],     b1_2[2*j + 1]};
        W2[j] = (v2f){w2_2[2*j],     w2_2[2*j + 1]};
    }
    const float b2_1s = b2_1[0], b2_2s = b2_2[0];
    const v2f zero2 = (v2f){0.0f, 0.0f};
    const char* const hcB   = (const char*)hc;
    const char* const hvB   = (const char*)hv;
    char*       const msgVB = (char*)msgV;
    char*       const msgCB = (char*)msgC;

    // ---- initial hv cache (valid for iter 0's phase 1A) ----
    float hvs[EPT];
    #pragma unroll
    for (int i = 0; i < EPT; ++i) hvs[i] = *(const float*)(hvB + aD[i]);

    for (int it = 0; it < NC; ++it) {
        // hc frozen for this whole iteration -> cache the 8 gathers
        float hcs[EPT];
        #pragma unroll
        for (int i = 0; i < EPT; ++i) hcs[i] = *(const float*)(hcB + aS[i]);

        // ===== phase 1 pass A: gather-free MLP (hcs+hvs cached) -> scatter msgV =====
        #pragma unroll
        for (int i = 0; i < EPT; ++i) {
            const float xj = hcs[i];
            const float xi = hvs[i];
            const v2f xj2 = (v2f){xj, xj}, xi2 = (v2f){xi, xi};
            v2f acc = (v2f){b2_1s, 0.0f};
            #pragma unroll
            for (int j = 0; j < 5; ++j) {
                v2f t = __builtin_elementwise_fma(C1[j], xi2, B1[j]);
                t = __builtin_elementwise_fma(A1[j], xj2, t);
                t = __builtin_elementwise_max(t, zero2);
                acc = __builtin_elementwise_fma(W1[j], t, acc);
            }
            *(float*)(msgVB + p1B[i]) = acc.x + acc.y;
        }
        __syncthreads();

        // ===== phase 1 pass B: var owner — aligned float4 gather + GRU =====
        {
            const int beg = beg_v[tid];
            const int deg = deg_v[tid];
            const float4* mp = (const float4*)&msgV[beg];
            float4 a4 = {0.0f, 0.0f, 0.0f, 0.0f};
            #pragma unroll
            for (int k = 0; k < 5; ++k) {           // covers deg <= 20
                if (4 * k < deg) {
                    const float4 q = mp[k];         // pads are zero
                    a4.x += q.x; a4.y += q.y; a4.z += q.z; a4.w += q.w;
                }
            }
            float hx = (a4.x + a4.y) + (a4.z + a4.w);
            for (int e = beg + 20; e < beg + deg; ++e) hx += msgV[e];  // rare
            const float xg = hvreg;
            float gi0 = fmaf(wih_1[0], xg, bih_1[0]);
            float gi1 = fmaf(wih_1[1], xg, bih_1[1]);
            float gi2 = fmaf(wih_1[2], xg, bih_1[2]);
            float gh0 = fmaf(whh_1[0], hx, bhh_1[0]);
            float gh1 = fmaf(whh_1[1], hx, bhh_1[1]);
            float gh2 = fmaf(whh_1[2], hx, bhh_1[2]);
            float r = sigmoid_f(gi0 + gh0);
            float z = sigmoid_f(gi1 + gh1);
            float n = tanh_f(fmaf(r, gh2, gi2));
            hvreg = fmaf(1.0f - z, n, z * hx);
            hv[tid] = hvreg;
        }
        __syncthreads();

        // ===== phase 2 pass A: gather fresh hv (cache for next iter), reuse hcs =====
        #pragma unroll
        for (int i = 0; i < EPT; ++i) hvs[i] = *(const float*)(hvB + aD[i]);
        #pragma unroll
        for (int i = 0; i < EPT; ++i) {
            const float xi = hcs[i];
            const float xj = hvs[i];
            const v2f xj2 = (v2f){xj, xj}, xi2 = (v2f){xi, xi};
            v2f acc = (v2f){b2_2s, 0.0f};
            #pragma unroll
            for (int j = 0; j < 5; ++j) {
                v2f t = __builtin_elementwise_fma(C2[j], xi2, B2[j]);
                t = __builtin_elementwise_fma(A2[j], xj2, t);
                t = __builtin_elementwise_max(t, zero2);
                acc = __builtin_elementwise_fma(W2[j], t, acc);
            }
            *(float*)(msgCB + p2B[i]) = acc.x + acc.y;
        }
        __syncthreads();

        // ===== phase 2 pass B: lane-pair per check — interleaved float4 chunks =====
        {
            const int c    = tid >> 1;
            const int half = tid & 1;
            const int beg = beg_c[c];
            const int deg = deg_c[c];
            const float4* mp = (const float4*)&msgC[beg];
            float4 a4 = {0.0f, 0.0f, 0.0f, 0.0f};
            #pragma unroll
            for (int k = 0; k < 4; ++k) {           // chunks half, half+2, ... covers deg <= 32
                const int ch = half + 2 * k;
                if (4 * ch < deg) {
                    const float4 q = mp[ch];        // pads are zero
                    a4.x += q.x; a4.y += q.y; a4.z += q.z; a4.w += q.w;
                }
            }
            float part = (a4.x + a4.y) + (a4.z + a4.w);
            for (int e = beg + 32 + half; e < beg + deg; e += 2) part += msgC[e];  // rare
            part += __shfl_xor(part, 1);
            if (half == 0) {
                const float hx = part;
                const float xg = hc[c];
                float gi0 = fmaf(wih_2[0], xg, bih_2[0]);
                float gi1 = fmaf(wih_2[1], xg, bih_2[1]);
                float gi2 = fmaf(wih_2[2], xg, bih_2[2]);
                float gh0 = fmaf(whh_2[0], hx, bhh_2[0]);
                float gh1 = fmaf(whh_2[1], hx, bhh_2[1]);
                float gh2 = fmaf(whh_2[2], hx, bhh_2[2]);
                float r = sigmoid_f(gi0 + gh0);
                float z = sigmoid_f(gi1 + gh1);
                float n = tanh_f(fmaf(r, gh2, gi2));
                hc[c] = fmaf(1.0f - z, n, z * hx);
            }
        }
        __syncthreads();
    }

    // ---- epilogue: out = clip(sigmoid(-h), eps, 1-eps) ----
    {
        float sgm = 1.0f / (1.0f + __expf(hvreg));
        out[base + ROWS + tid] = fminf(fmaxf(sgm, EPSF), 1.0f - EPSF);
    }
    if (tid < ROWS) {
        float sgm = 1.0f / (1.0f + __expf(hc[tid]));
        out[base + tid] = fminf(fmaxf(sgm, EPSF), 1.0f - EPSF);
    }
}

extern "C" void kernel_launch(void* const* d_in, const int* in_sizes, int n_in,
                              void* d_out, int out_size, void* d_ws, size_t ws_size,
                              hipStream_t stream) {
    const float* x    = (const float*)d_in[0];
    const int*   eidx = (const int*)d_in[1];
    gnni_kernel<<<BATCH, NT, 0, stream>>>(
        x, eidx,
        (const float*)d_in[2],  (const float*)d_in[3],
        (const float*)d_in[4],  (const float*)d_in[5],
        (const float*)d_in[6],  (const float*)d_in[7],
        (const float*)d_in[8],  (const float*)d_in[9],
        (const float*)d_in[10], (const float*)d_in[11],
        (const float*)d_in[12], (const float*)d_in[13],
        (const float*)d_in[14], (const float*)d_in[15],
        (const float*)d_in[16], (const float*)d_in[17],
        (float*)d_out);
}